// Round 3
// baseline (4130.698 us; speedup 1.0000x reference)
//
#include <hip/hip_runtime.h>
#include <hip/hip_bf16.h>

#define NUM_USER 300000
#define NUM_ITEM 200000
#define NTOT (NUM_USER + NUM_ITEM)
#define D 64
#define RPB 128                         // rows per bucket
#define NB ((NTOT + RPB - 1) / RPB)     // 3907 buckets
#define NBLK 256                        // edge-chunk blocks for hist/scatter
#define ASTR 65                         // padded LDS acc row stride (floats)

// ---------- phase 1a: per-block bucket histogram (LDS atomics only) ----------

__global__ __launch_bounds__(256) void hist_bucket(
    const int* __restrict__ rows, int* __restrict__ blockhist, int nnz)
{
    __shared__ int h[NB];   // 15.6 KB
    for (int i = threadIdx.x; i < NB; i += 256) h[i] = 0;
    __syncthreads();
    int chunk = (nnz + NBLK - 1) / NBLK;
    int lo = blockIdx.x * chunk;
    int hi = min(lo + chunk, nnz);
    for (int e = lo + threadIdx.x; e < hi; e += 256)
        atomicAdd(&h[__builtin_nontemporal_load(&rows[e]) >> 7], 1);
    __syncthreads();
    for (int i = threadIdx.x; i < NB; i += 256)
        blockhist[blockIdx.x * NB + i] = h[i];
}

// ---------- phase 1b: per-bucket exclusive scan across blocks ----------

__global__ __launch_bounds__(256) void colscan(
    int* __restrict__ blockhist, int* __restrict__ coltotal)
{
    int kb = blockIdx.x * 256 + threadIdx.x;
    if (kb >= NB) return;
    int sum = 0;
    for (int b = 0; b < NBLK; b++) {
        int v = blockhist[b * NB + kb];   // coalesced across lanes
        blockhist[b * NB + kb] = sum;
        sum += v;
    }
    coltotal[kb] = sum;
}

// ---------- phase 1c: exclusive scan of bucket totals (single block) ----------

__global__ __launch_bounds__(256) void bucketscan(
    const int* __restrict__ coltotal, int* __restrict__ bucketbase, int nnz)
{
    __shared__ int s[256];
    int t = threadIdx.x;
    int local[16];
    int sum = 0;
    #pragma unroll
    for (int i = 0; i < 16; i++) {
        int idx = t * 16 + i;
        int c = (idx < NB) ? coltotal[idx] : 0;
        local[i] = sum;       // exclusive within thread
        sum += c;
    }
    s[t] = sum;
    __syncthreads();
    int v = sum;
    for (int off = 1; off < 256; off <<= 1) {
        int add = (t >= off) ? s[t - off] : 0;
        __syncthreads();
        s[t] += add;
        __syncthreads();
    }
    int base = s[t] - v;      // exclusive across block
    #pragma unroll
    for (int i = 0; i < 16; i++) {
        int idx = t * 16 + i;
        if (idx < NB) bucketbase[idx] = base + local[i];
    }
    if (t == 255) bucketbase[NB] = base + sum;   // == nnz
}

// ---------- phase 1d: deterministic scatter into bucket segments ----------
// FAST: rec2[pos] = {(lrow<<19)|col, val}  (8B self-contained record)
// SLOW: order[pos] = (lrow<<24)|edge_id    (fallback if workspace small)

template<bool FAST>
__global__ __launch_bounds__(256) void scatter_bucket(
    const int* __restrict__ rows, const int* __restrict__ cols,
    const float* __restrict__ vals,
    const int* __restrict__ blockhist, const int* __restrict__ bucketbase,
    int* __restrict__ order, int2* __restrict__ rec2, int nnz)
{
    __shared__ int cur[NB];   // 15.6 KB
    for (int i = threadIdx.x; i < NB; i += 256)
        cur[i] = blockhist[blockIdx.x * NB + i] + bucketbase[i];
    __syncthreads();
    int chunk = (nnz + NBLK - 1) / NBLK;
    int lo = blockIdx.x * chunk;
    int hi = min(lo + chunk, nnz);
    for (int e = lo + threadIdx.x; e < hi; e += 256) {
        int r = __builtin_nontemporal_load(&rows[e]);
        int pos = atomicAdd(&cur[r >> 7], 1);     // LDS atomic, fast
        if (FAST) {
            int   c = __builtin_nontemporal_load(&cols[e]);
            float v = __builtin_nontemporal_load(&vals[e]);
            rec2[pos] = make_int2(((r & (RPB - 1)) << 19) | c,
                                  __float_as_int(v));
        } else {
            order[pos] = ((r & (RPB - 1)) << 24) | e;
        }
    }
}

// ---------- phase 2a: bucket accumulate into LDS, dump agg to out ----------
// Quarter-wave per edge: 16 lanes x float4 = one 256B row; one VMEM
// instruction covers 4 edges (1KB) -> 4x MLP per vmcnt slot.

template<bool FAST>
__global__ __launch_bounds__(256) void accum_kernel(
    const float* __restrict__ users_emb, const float* __restrict__ items_emb,
    const float* __restrict__ vals, const int* __restrict__ cols,
    const int* __restrict__ bucketbase, const int* __restrict__ order,
    const long long* __restrict__ rec2, float* __restrict__ out)
{
    __shared__ float acc[RPB * ASTR];   // 33.3 KB, acc[lrow*65 + dim]
    int tid = threadIdx.x;
    for (int i = tid; i < RPB * ASTR; i += 256) acc[i] = 0.f;
    __syncthreads();

    int kb = blockIdx.x;
    int start = bucketbase[kb];
    int end   = bucketbase[kb + 1];
    int lane = tid & 63;
    int wid  = tid >> 6;
    int sub  = lane >> 4;        // which edge of the 4-group this lane serves
    int qi   = lane & 15;        // 16B chunk within the 256B row

    for (int base = start + wid * 64; base < end; base += 256) {
        int m  = end - base;
        int mm = m < 64 ? m : 64;
        int ck = 0; float v = 0.f;
        if (lane < mm) {
            if (FAST) {
                long long rc = __builtin_nontemporal_load(&rec2[base + lane]);
                ck = (int)(rc & 0xffffffffLL);
                v  = __int_as_float((int)(rc >> 32));
            } else {
                int rec  = __builtin_nontemporal_load(&order[base + lane]);
                int e    = rec & 0xFFFFFF;
                int lrow = rec >> 24;
                ck = cols[e] | (lrow << 19);     // col < 2^19, lrow bits 19..25
                v  = vals[e];
            }
        }
        int groups = (mm + 3) >> 2;
        #pragma unroll 4
        for (int j = 0; j < groups; j++) {
            int idx  = (j << 2) + sub;
            int ckj  = __shfl(ck, idx);          // lanes with idx>=mm get 0
            float vj = __shfl(v, idx);
            int cj = ckj & 0x7FFFF;
            int lr = ckj >> 19;
            const float* src = (cj < NUM_USER)
                ? users_emb + (size_t)cj * D
                : items_emb + (size_t)(cj - NUM_USER) * D;
            float4 e4 = *(const float4*)(src + (qi << 2));
            int ab = lr * ASTR + (qi << 2);
            atomicAdd(&acc[ab + 0], vj * e4.x);
            atomicAdd(&acc[ab + 1], vj * e4.y);
            atomicAdd(&acc[ab + 2], vj * e4.z);
            atomicAdd(&acc[ab + 3], vj * e4.w);
        }
    }
    __syncthreads();

    // coalesced float4 dump of the padded tile
    size_t row0 = (size_t)kb * RPB;
    float4* o4 = (float4*)(out + row0 * D);
    for (int i = tid; i < RPB * (D / 4); i += 256) {
        int row = i >> 4, c4 = (i & 15) << 2;
        size_t grow = row0 + row;
        if (grow < NTOT) {
            float4 o;
            o.x = acc[row * ASTR + c4 + 0];
            o.y = acc[row * ASTR + c4 + 1];
            o.z = acc[row * ASTR + c4 + 2];
            o.w = acc[row * ASTR + c4 + 3];
            o4[i] = o;
        }
    }
}

// ---------- phase 2b: in-place out_row = leaky_relu(agg_row @ w) ----------

__global__ __launch_bounds__(256) void rowgemm_kernel(
    float* __restrict__ out, const float* __restrict__ w, int n)
{
    __shared__ float ws[D * D];   // 16 KB
    __shared__ float as[16 * D];  // 4 KB
    int tid = threadIdx.x;

    const float4* w4 = (const float4*)w;
    float4* ws4 = (float4*)ws;
    #pragma unroll
    for (int i = 0; i < 4; i++) ws4[tid + i * 256] = w4[tid + i * 256];

    size_t row0 = (size_t)blockIdx.x * 16;
    ((float4*)as)[tid] = ((const float4*)(out + row0 * D))[tid];
    __syncthreads();

    int col  = tid & 63;
    int rsub = tid >> 6;
    float res[4];
    #pragma unroll
    for (int rr = 0; rr < 4; rr++) {
        int row = rr * 4 + rsub;
        float acc = 0.f;
        #pragma unroll
        for (int k = 0; k < D; k++) {
            acc = fmaf(as[row * D + k], ws[k * D + col], acc);
        }
        res[rr] = acc > 0.f ? acc : 0.2f * acc;
    }
    #pragma unroll
    for (int rr = 0; rr < 4; rr++) {
        int row = rr * 4 + rsub;
        out[(row0 + row) * D + col] = res[rr];
    }
}

extern "C" void kernel_launch(void* const* d_in, const int* in_sizes, int n_in,
                              void* d_out, int out_size, void* d_ws, size_t ws_size,
                              hipStream_t stream) {
    const float* users_emb = (const float*)d_in[0];
    const float* items_emb = (const float*)d_in[1];
    const float* vals      = (const float*)d_in[2];
    const float* w         = (const float*)d_in[3];
    const int*   rows      = (const int*)d_in[4];
    const int*   cols      = (const int*)d_in[5];
    float* out = (float*)d_out;

    int nnz = in_sizes[2];
    int n   = NTOT;

    // workspace layout (bytes):
    //   blockhist  @ 0        : NBLK*NB ints  (3.8 MB)
    //   coltotal   @ 4 MB     : NB ints
    //   bucketbase @ 4 MB+64K : NB+1 ints
    //   rec2/order @ 8 MB     : nnz*8 B fast (80 MB) / nnz*4 B slow (40 MB)
    char* ws = (char*)d_ws;
    int* blockhist  = (int*)(ws);
    int* coltotal   = (int*)(ws + (4ull << 20));
    int* bucketbase = (int*)(ws + (4ull << 20) + (64ull << 10));
    void* recbuf    = (void*)(ws + (8ull << 20));

    bool fast = ws_size >= (8ull << 20) + (size_t)nnz * 8ull;

    hist_bucket<<<NBLK, 256, 0, stream>>>(rows, blockhist, nnz);
    colscan<<<(NB + 255) / 256, 256, 0, stream>>>(blockhist, coltotal);
    bucketscan<<<1, 256, 0, stream>>>(coltotal, bucketbase, nnz);

    if (fast) {
        scatter_bucket<true><<<NBLK, 256, 0, stream>>>(
            rows, cols, vals, blockhist, bucketbase,
            nullptr, (int2*)recbuf, nnz);
        accum_kernel<true><<<NB, 256, 0, stream>>>(
            users_emb, items_emb, vals, cols, bucketbase,
            nullptr, (const long long*)recbuf, out);
    } else {
        scatter_bucket<false><<<NBLK, 256, 0, stream>>>(
            rows, cols, vals, blockhist, bucketbase,
            (int*)recbuf, nullptr, nnz);
        accum_kernel<false><<<NB, 256, 0, stream>>>(
            users_emb, items_emb, vals, cols, bucketbase,
            (const int*)recbuf, nullptr, out);
    }

    rowgemm_kernel<<<n / 16, 256, 0, stream>>>(out, w, n);
}

// Round 6
// 4081.065 us; speedup vs baseline: 1.0122x; 1.0122x over previous
//
#include <hip/hip_runtime.h>
#include <hip/hip_bf16.h>

#define NUM_USER 300000
#define NUM_ITEM 200000
#define NTOT (NUM_USER + NUM_ITEM)
#define D 64
#define RPB 128                         // rows per bucket
#define NB ((NTOT + RPB - 1) / RPB)     // 3907 buckets
#define NBLK 256                        // edge-chunk blocks for hist/scatter
#define ASTR 65                         // padded LDS acc row stride (floats)
#define AW 8                            // waves per accum block (512 threads)

// ---------- phase 1a: per-block bucket histogram (LDS atomics only) ----------

__global__ __launch_bounds__(256) void hist_bucket(
    const int* __restrict__ rows, int* __restrict__ blockhist, int nnz)
{
    __shared__ int h[NB];   // 15.6 KB
    for (int i = threadIdx.x; i < NB; i += 256) h[i] = 0;
    __syncthreads();
    int chunk = (nnz + NBLK - 1) / NBLK;
    int lo = blockIdx.x * chunk;
    int hi = min(lo + chunk, nnz);
    for (int e = lo + threadIdx.x; e < hi; e += 256)
        atomicAdd(&h[__builtin_nontemporal_load(&rows[e]) >> 7], 1);
    __syncthreads();
    for (int i = threadIdx.x; i < NB; i += 256)
        blockhist[blockIdx.x * NB + i] = h[i];
}

// ---------- phase 1b: per-bucket exclusive scan across blocks ----------

__global__ __launch_bounds__(256) void colscan(
    int* __restrict__ blockhist, int* __restrict__ coltotal)
{
    int kb = blockIdx.x * 256 + threadIdx.x;
    if (kb >= NB) return;
    int sum = 0;
    for (int b = 0; b < NBLK; b++) {
        int v = blockhist[b * NB + kb];   // coalesced across lanes
        blockhist[b * NB + kb] = sum;
        sum += v;
    }
    coltotal[kb] = sum;
}

// ---------- phase 1c: exclusive scan of bucket totals (single block) ----------

__global__ __launch_bounds__(256) void bucketscan(
    const int* __restrict__ coltotal, int* __restrict__ bucketbase, int nnz)
{
    __shared__ int s[256];
    int t = threadIdx.x;
    int local[16];
    int sum = 0;
    #pragma unroll
    for (int i = 0; i < 16; i++) {
        int idx = t * 16 + i;
        int c = (idx < NB) ? coltotal[idx] : 0;
        local[i] = sum;       // exclusive within thread
        sum += c;
    }
    s[t] = sum;
    __syncthreads();
    int v = sum;
    for (int off = 1; off < 256; off <<= 1) {
        int add = (t >= off) ? s[t - off] : 0;
        __syncthreads();
        s[t] += add;
        __syncthreads();
    }
    int base = s[t] - v;      // exclusive across block
    #pragma unroll
    for (int i = 0; i < 16; i++) {
        int idx = t * 16 + i;
        if (idx < NB) bucketbase[idx] = base + local[i];
    }
    if (t == 255) bucketbase[NB] = base + sum;   // == nnz
}

// ---------- phase 1d: deterministic scatter into bucket segments ----------
// FAST (needs ws >= 88MB): rec2[pos] = {(lrow<<19)|col, val}  (8B record)
// SLOW (48MB layout, proven): order[pos] = (lrow<<24)|edge_id

template<bool FAST>
__global__ __launch_bounds__(256) void scatter_bucket(
    const int* __restrict__ rows, const int* __restrict__ cols,
    const float* __restrict__ vals,
    const int* __restrict__ blockhist, const int* __restrict__ bucketbase,
    int* __restrict__ order, int2* __restrict__ rec2, int nnz)
{
    __shared__ int cur[NB];   // 15.6 KB
    for (int i = threadIdx.x; i < NB; i += 256)
        cur[i] = blockhist[blockIdx.x * NB + i] + bucketbase[i];
    __syncthreads();
    int chunk = (nnz + NBLK - 1) / NBLK;
    int lo = blockIdx.x * chunk;
    int hi = min(lo + chunk, nnz);
    for (int e = lo + threadIdx.x; e < hi; e += 256) {
        int r = __builtin_nontemporal_load(&rows[e]);
        int pos = atomicAdd(&cur[r >> 7], 1);     // LDS atomic, fast
        if (FAST) {
            int   c = __builtin_nontemporal_load(&cols[e]);
            float v = __builtin_nontemporal_load(&vals[e]);
            rec2[pos] = make_int2(((r & (RPB - 1)) << 19) | c,
                                  __float_as_int(v));
        } else {
            order[pos] = ((r & (RPB - 1)) << 24) | e;
        }
    }
}

// ---------- phase 2a: bucket accumulate into LDS, dump agg to out ----------
// Quarter-wave per edge, NO cross-lane ops: every address is a pure
// function of induction variables, so rec->row->ds_add chains of
// different iterations are independent and pipeline deep.
// 512 threads, 33.3 KB LDS -> up to 4 blocks/CU * 8 waves.

template<bool FAST>
__global__ __launch_bounds__(512) void accum_kernel(
    const float* __restrict__ users_emb, const float* __restrict__ items_emb,
    const float* __restrict__ vals, const int* __restrict__ cols,
    const long long* __restrict__ rec2, const int* __restrict__ order,
    const int* __restrict__ bucketbase, float* __restrict__ out)
{
    __shared__ float acc[RPB * ASTR];   // 33.3 KB, acc[lrow*65 + dim]
    int tid = threadIdx.x;
    for (int i = tid; i < RPB * ASTR; i += 512) acc[i] = 0.f;
    __syncthreads();

    int kb = blockIdx.x;
    int start = bucketbase[kb];
    int end   = bucketbase[kb + 1];
    int lane = tid & 63;
    int wid  = tid >> 6;          // 0..7
    int sub  = lane >> 4;         // which of 4 edges this quarter-wave owns
    int qi   = lane & 15;         // 16B chunk within the 256B row

    int span = end - start;
    int T = (span + (AW * 4 - 1)) / (AW * 4);   // uniform trips across waves
    int e0 = start + wid * 4 + sub;

    #pragma unroll 2
    for (int it = 0; it < T; it++) {
        int e  = e0 + it * (AW * 4);
        int ec = max(start, min(e, end - 1));     // clamp; OOB lanes add 0
        int ck; float v;
        if (FAST) {
            long long rc = __builtin_nontemporal_load(&rec2[ec]);
            ck = (int)(rc & 0xffffffffLL);
            v  = (e < end) ? __int_as_float((int)(rc >> 32)) : 0.f;
        } else {
            int rec  = __builtin_nontemporal_load(&order[ec]);
            int eid  = rec & 0xFFFFFF;
            int lrow = rec >> 24;
            ck = __builtin_nontemporal_load(&cols[eid]) | (lrow << 19);
            v  = (e < end) ? __builtin_nontemporal_load(&vals[eid]) : 0.f;
        }
        int cj = ck & 0x7FFFF;
        int lr = (ck >> 19) & (RPB - 1);
        const float* src = (cj < NUM_USER)
            ? users_emb + (size_t)cj * D
            : items_emb + (size_t)(cj - NUM_USER) * D;
        float4 e4 = *(const float4*)(src + (qi << 2));
        int ab = lr * ASTR + (qi << 2);
        atomicAdd(&acc[ab + 0], v * e4.x);
        atomicAdd(&acc[ab + 1], v * e4.y);
        atomicAdd(&acc[ab + 2], v * e4.z);
        atomicAdd(&acc[ab + 3], v * e4.w);
    }
    __syncthreads();

    // coalesced float4 dump of the padded tile
    size_t row0 = (size_t)kb * RPB;
    float4* o4 = (float4*)(out + row0 * D);
    for (int i = tid; i < RPB * (D / 4); i += 512) {
        int row = i >> 4, c4 = (i & 15) << 2;
        size_t grow = row0 + row;
        if (grow < NTOT) {
            float4 o;
            o.x = acc[row * ASTR + c4 + 0];
            o.y = acc[row * ASTR + c4 + 1];
            o.z = acc[row * ASTR + c4 + 2];
            o.w = acc[row * ASTR + c4 + 3];
            o4[i] = o;
        }
    }
}

// ---------- phase 2b: in-place out_row = leaky_relu(agg_row @ w) ----------

__global__ __launch_bounds__(256) void rowgemm_kernel(
    float* __restrict__ out, const float* __restrict__ w, int n)
{
    __shared__ float ws[D * D];   // 16 KB
    __shared__ float as[16 * D];  // 4 KB
    int tid = threadIdx.x;

    const float4* w4 = (const float4*)w;
    float4* ws4 = (float4*)ws;
    #pragma unroll
    for (int i = 0; i < 4; i++) ws4[tid + i * 256] = w4[tid + i * 256];

    size_t row0 = (size_t)blockIdx.x * 16;
    ((float4*)as)[tid] = ((const float4*)(out + row0 * D))[tid];
    __syncthreads();

    int col  = tid & 63;
    int rsub = tid >> 6;
    float res[4];
    #pragma unroll
    for (int rr = 0; rr < 4; rr++) {
        int row = rr * 4 + rsub;
        float acc = 0.f;
        #pragma unroll
        for (int k = 0; k < D; k++) {
            acc = fmaf(as[row * D + k], ws[k * D + col], acc);
        }
        res[rr] = acc > 0.f ? acc : 0.2f * acc;
    }
    #pragma unroll
    for (int rr = 0; rr < 4; rr++) {
        int row = rr * 4 + rsub;
        out[(row0 + row) * D + col] = res[rr];
    }
}

extern "C" void kernel_launch(void* const* d_in, const int* in_sizes, int n_in,
                              void* d_out, int out_size, void* d_ws, size_t ws_size,
                              hipStream_t stream) {
    const float* users_emb = (const float*)d_in[0];
    const float* items_emb = (const float*)d_in[1];
    const float* vals      = (const float*)d_in[2];
    const float* w         = (const float*)d_in[3];
    const int*   rows      = (const int*)d_in[4];
    const int*   cols      = (const int*)d_in[5];
    float* out = (float*)d_out;

    int nnz = in_sizes[2];
    int n   = NTOT;

    // workspace layout (bytes):
    //   blockhist  @ 0        : NBLK*NB ints  (3.8 MB)
    //   coltotal   @ 4 MB     : NB ints
    //   bucketbase @ 4 MB+64K : NB+1 ints
    //   rec2/order @ 8 MB     : nnz*8 B fast (88 MB total) / nnz*4 B slow (48 MB)
    char* ws = (char*)d_ws;
    int* blockhist  = (int*)(ws);
    int* coltotal   = (int*)(ws + (4ull << 20));
    int* bucketbase = (int*)(ws + (4ull << 20) + (64ull << 10));
    void* recbuf    = (void*)(ws + (8ull << 20));

    bool fast = ws_size >= (8ull << 20) + (size_t)nnz * 8ull;

    hist_bucket<<<NBLK, 256, 0, stream>>>(rows, blockhist, nnz);
    colscan<<<(NB + 255) / 256, 256, 0, stream>>>(blockhist, coltotal);
    bucketscan<<<1, 256, 0, stream>>>(coltotal, bucketbase, nnz);

    if (fast) {
        scatter_bucket<true><<<NBLK, 256, 0, stream>>>(
            rows, cols, vals, blockhist, bucketbase,
            nullptr, (int2*)recbuf, nnz);
        accum_kernel<true><<<NB, 512, 0, stream>>>(
            users_emb, items_emb, vals, cols,
            (const long long*)recbuf, nullptr, bucketbase, out);
    } else {
        scatter_bucket<false><<<NBLK, 256, 0, stream>>>(
            rows, cols, vals, blockhist, bucketbase,
            (int*)recbuf, nullptr, nnz);
        accum_kernel<false><<<NB, 512, 0, stream>>>(
            users_emb, items_emb, vals, cols,
            nullptr, (const int*)recbuf, bucketbase, out);
    }

    rowgemm_kernel<<<n / 16, 256, 0, stream>>>(out, w, n);
}

// Round 7
// 1575.013 us; speedup vs baseline: 2.6226x; 2.5911x over previous
//
#include <hip/hip_runtime.h>
#include <hip/hip_bf16.h>

#define NUM_USER 300000
#define NUM_ITEM 200000
#define NTOT (NUM_USER + NUM_ITEM)
#define D 64
#define RPB 128                         // rows per bucket
#define NB ((NTOT + RPB - 1) / RPB)     // 3907 buckets
#define NBLK 256                        // edge-chunk blocks for hist/scatter
#define ASTR 65                         // padded LDS acc row stride (fallback)
#define AW 8                            // waves per accum block (fallback)
#define SCAN_ELEMS 2048

// ---------- phase 1a: per-block bucket histogram (LDS atomics only) ----------

__global__ __launch_bounds__(256) void hist_bucket(
    const int* __restrict__ rows, int* __restrict__ blockhist, int nnz)
{
    __shared__ int h[NB];   // 15.6 KB
    for (int i = threadIdx.x; i < NB; i += 256) h[i] = 0;
    __syncthreads();
    int chunk = (nnz + NBLK - 1) / NBLK;
    int lo = blockIdx.x * chunk;
    int hi = min(lo + chunk, nnz);
    for (int e = lo + threadIdx.x; e < hi; e += 256)
        atomicAdd(&h[__builtin_nontemporal_load(&rows[e]) >> 7], 1);
    __syncthreads();
    for (int i = threadIdx.x; i < NB; i += 256)
        blockhist[blockIdx.x * NB + i] = h[i];
}

// ---------- phase 1b: per-bucket exclusive scan across blocks ----------

__global__ __launch_bounds__(256) void colscan(
    int* __restrict__ blockhist, int* __restrict__ coltotal)
{
    int kb = blockIdx.x * 256 + threadIdx.x;
    if (kb >= NB) return;
    int sum = 0;
    for (int b = 0; b < NBLK; b++) {
        int v = blockhist[b * NB + kb];   // coalesced across lanes
        blockhist[b * NB + kb] = sum;
        sum += v;
    }
    coltotal[kb] = sum;
}

// ---------- phase 1c: exclusive scan of bucket totals (single block) ----------

__global__ __launch_bounds__(256) void bucketscan(
    const int* __restrict__ coltotal, int* __restrict__ bucketbase, int nnz)
{
    __shared__ int s[256];
    int t = threadIdx.x;
    int local[16];
    int sum = 0;
    #pragma unroll
    for (int i = 0; i < 16; i++) {
        int idx = t * 16 + i;
        int c = (idx < NB) ? coltotal[idx] : 0;
        local[i] = sum;       // exclusive within thread
        sum += c;
    }
    s[t] = sum;
    __syncthreads();
    int v = sum;
    for (int off = 1; off < 256; off <<= 1) {
        int add = (t >= off) ? s[t - off] : 0;
        __syncthreads();
        s[t] += add;
        __syncthreads();
    }
    int base = s[t] - v;      // exclusive across block
    #pragma unroll
    for (int i = 0; i < 16; i++) {
        int idx = t * 16 + i;
        if (idx < NB) bucketbase[idx] = base + local[i];
    }
    if (t == 255) bucketbase[NB] = base + sum;   // == nnz
}

// ---------- phase 1d: deterministic scatter into bucket segments ----------
// FAST: rec2[pos] = {(lrow<<19)|col, val}  (8B self-contained record)
// SLOW: order[pos] = (lrow<<24)|edge_id    (fallback if workspace < 88MB)

template<bool FAST>
__global__ __launch_bounds__(256) void scatter_bucket(
    const int* __restrict__ rows, const int* __restrict__ cols,
    const float* __restrict__ vals,
    const int* __restrict__ blockhist, const int* __restrict__ bucketbase,
    int* __restrict__ order, int2* __restrict__ rec2, int nnz)
{
    __shared__ int cur[NB];   // 15.6 KB
    for (int i = threadIdx.x; i < NB; i += 256)
        cur[i] = blockhist[blockIdx.x * NB + i] + bucketbase[i];
    __syncthreads();
    int chunk = (nnz + NBLK - 1) / NBLK;
    int lo = blockIdx.x * chunk;
    int hi = min(lo + chunk, nnz);
    for (int e = lo + threadIdx.x; e < hi; e += 256) {
        int r = __builtin_nontemporal_load(&rows[e]);
        int pos = atomicAdd(&cur[r >> 7], 1);     // LDS atomic, fast
        if (FAST) {
            int   c = __builtin_nontemporal_load(&cols[e]);
            float v = __builtin_nontemporal_load(&vals[e]);
            rec2[pos] = make_int2(((r & (RPB - 1)) << 19) | c,
                                  __float_as_int(v));
        } else {
            order[pos] = ((r & (RPB - 1)) << 24) | e;
        }
    }
}

// ---------- phase 1e: per-row counts from bucket-sorted records ----------

__global__ __launch_bounds__(256) void rowhist(
    const long long* __restrict__ rec2, const int* __restrict__ bucketbase,
    int* __restrict__ rowcnt)
{
    __shared__ int h[RPB];
    int t = threadIdx.x;
    if (t < RPB) h[t] = 0;
    __syncthreads();
    int kb = blockIdx.x;
    int start = bucketbase[kb], end = bucketbase[kb + 1];
    for (int i = start + t; i < end; i += 256) {
        int key = (int)(__builtin_nontemporal_load(&rec2[i]) & 0xffffffffLL);
        atomicAdd(&h[(key >> 19) & (RPB - 1)], 1);
    }
    __syncthreads();
    int row0 = kb * RPB;
    if (t < RPB && row0 + t < NTOT) rowcnt[row0 + t] = h[t];
}

// ---------- phase 1f: exclusive scan rowcnt -> rowptr (3 kernels, proven) ----

__global__ __launch_bounds__(256) void scan_reduce(
    const int* __restrict__ cnt, int* __restrict__ bsums, int n)
{
    __shared__ int s[256];
    int base = blockIdx.x * SCAN_ELEMS;
    int sum = 0;
    for (int i = threadIdx.x; i < SCAN_ELEMS; i += 256) {
        int idx = base + i;
        sum += (idx < n) ? cnt[idx] : 0;
    }
    s[threadIdx.x] = sum;
    __syncthreads();
    for (int off = 128; off > 0; off >>= 1) {
        if (threadIdx.x < off) s[threadIdx.x] += s[threadIdx.x + off];
        __syncthreads();
    }
    if (threadIdx.x == 0) bsums[blockIdx.x] = s[0];
}

__global__ __launch_bounds__(256) void scan_bsums(
    int* __restrict__ bsums, int* __restrict__ ptr, int B, int n, int nnz)
{
    __shared__ int s[256];
    int t = threadIdx.x;
    int v = (t < B) ? bsums[t] : 0;
    s[t] = v;
    __syncthreads();
    for (int off = 1; off < 256; off <<= 1) {
        int add = (t >= off) ? s[t - off] : 0;
        __syncthreads();
        s[t] += add;
        __syncthreads();
    }
    if (t < B) bsums[t] = s[t] - v;  // exclusive
    if (t == 0) ptr[n] = nnz;
}

__global__ __launch_bounds__(256) void scan_final(
    const int* __restrict__ cnt, const int* __restrict__ bsums,
    int* __restrict__ ptr, int n)
{
    __shared__ int s[256];
    int base = blockIdx.x * SCAN_ELEMS;
    int t = threadIdx.x;
    int local[8];
    int mysum = 0;
    #pragma unroll
    for (int i = 0; i < 8; i++) {
        int idx = base + t * 8 + i;
        int c = (idx < n) ? cnt[idx] : 0;
        local[i] = mysum;   // exclusive within thread
        mysum += c;
    }
    s[t] = mysum;
    __syncthreads();
    int v = mysum;
    for (int off = 1; off < 256; off <<= 1) {
        int add = (t >= off) ? s[t - off] : 0;
        __syncthreads();
        s[t] += add;
        __syncthreads();
    }
    int thread_base = bsums[blockIdx.x] + s[t] - v;  // exclusive across block
    #pragma unroll
    for (int i = 0; i < 8; i++) {
        int idx = base + t * 8 + i;
        if (idx < n) ptr[idx] = thread_base + local[i];
    }
}

// ---------- phase 1g: row-sort within bucket: rec2 -> rec3 = {col,val} ------
// rowptr[row0] == bucketbase[kb] (scans agree), so writes stay in-bucket.

__global__ __launch_bounds__(256) void rescatter(
    const long long* __restrict__ rec2, const int* __restrict__ bucketbase,
    const int* __restrict__ rowptr, long long* __restrict__ rec3)
{
    __shared__ int cur[RPB];
    int t = threadIdx.x;
    int kb = blockIdx.x;
    int row0 = kb * RPB;
    if (t < RPB) cur[t] = (row0 + t < NTOT) ? rowptr[row0 + t] : 0;
    __syncthreads();
    int start = bucketbase[kb], end = bucketbase[kb + 1];
    for (int i = start + t; i < end; i += 256) {
        long long rc = __builtin_nontemporal_load(&rec2[i]);
        int key = (int)(rc & 0xffffffffLL);
        int lr  = (key >> 19) & (RPB - 1);
        int pos = atomicAdd(&cur[lr], 1);        // LDS atomic
        long long outrec = (rc & 0xffffffff00000000LL)
                         | (unsigned int)(key & 0x7FFFF);
        rec3[pos] = outrec;                       // in-bucket window, L2-local
    }
}

// ---------- phase 2a: gather, one wave per row, REGISTER accumulation -------
// Proven-fast structure (R0 baseline), minus the cols/vals/order hops.

__global__ __launch_bounds__(256) void gather_rows(
    const float* __restrict__ users_emb, const float* __restrict__ items_emb,
    const long long* __restrict__ rec3, const int* __restrict__ rowptr,
    float* __restrict__ out, int n)
{
    int r = blockIdx.x * 4 + (threadIdx.x >> 6);
    if (r >= n) return;
    int lane = threadIdx.x & 63;
    int start = rowptr[r];
    int end   = rowptr[r + 1];
    float acc = 0.f;
    for (int base = start; base < end; base += 64) {
        int m = end - base;
        int c = 0; float v = 0.f;
        if (lane < m) {
            long long rc = __builtin_nontemporal_load(&rec3[base + lane]);
            c = (int)(rc & 0xffffffffLL);
            v = __int_as_float((int)(rc >> 32));
        }
        int cnt = m < 64 ? m : 64;
        for (int j = 0; j < cnt; j++) {
            int   cj = __shfl(c, j);
            float vj = __shfl(v, j);
            const float* src = (cj < NUM_USER)
                ? users_emb + (size_t)cj * D
                : items_emb + (size_t)(cj - NUM_USER) * D;
            acc = fmaf(vj, src[lane], acc);  // 256B coalesced gather per wave
        }
    }
    out[(size_t)r * D + lane] = acc;
}

// ---------- fallback phase 2a (ws too small): bucket accum via LDS ----------

template<bool FAST>
__global__ __launch_bounds__(512) void accum_kernel(
    const float* __restrict__ users_emb, const float* __restrict__ items_emb,
    const float* __restrict__ vals, const int* __restrict__ cols,
    const long long* __restrict__ rec2, const int* __restrict__ order,
    const int* __restrict__ bucketbase, float* __restrict__ out)
{
    __shared__ float acc[RPB * ASTR];   // 33.3 KB
    int tid = threadIdx.x;
    for (int i = tid; i < RPB * ASTR; i += 512) acc[i] = 0.f;
    __syncthreads();

    int kb = blockIdx.x;
    int start = bucketbase[kb];
    int end   = bucketbase[kb + 1];
    int lane = tid & 63;
    int wid  = tid >> 6;
    int sub  = lane >> 4;
    int qi   = lane & 15;

    int span = end - start;
    int T = (span + (AW * 4 - 1)) / (AW * 4);
    int e0 = start + wid * 4 + sub;

    for (int it = 0; it < T; it++) {
        int e  = e0 + it * (AW * 4);
        int ec = max(start, min(e, end - 1));
        int ck; float v;
        if (FAST) {
            long long rc = __builtin_nontemporal_load(&rec2[ec]);
            ck = (int)(rc & 0xffffffffLL);
            v  = (e < end) ? __int_as_float((int)(rc >> 32)) : 0.f;
        } else {
            int rec  = __builtin_nontemporal_load(&order[ec]);
            int eid  = rec & 0xFFFFFF;
            int lrow = rec >> 24;
            ck = __builtin_nontemporal_load(&cols[eid]) | (lrow << 19);
            v  = (e < end) ? __builtin_nontemporal_load(&vals[eid]) : 0.f;
        }
        int cj = ck & 0x7FFFF;
        int lr = (ck >> 19) & (RPB - 1);
        const float* src = (cj < NUM_USER)
            ? users_emb + (size_t)cj * D
            : items_emb + (size_t)(cj - NUM_USER) * D;
        float4 e4 = *(const float4*)(src + (qi << 2));
        int ab = lr * ASTR + (qi << 2);
        atomicAdd(&acc[ab + 0], v * e4.x);
        atomicAdd(&acc[ab + 1], v * e4.y);
        atomicAdd(&acc[ab + 2], v * e4.z);
        atomicAdd(&acc[ab + 3], v * e4.w);
    }
    __syncthreads();

    size_t row0 = (size_t)kb * RPB;
    float4* o4 = (float4*)(out + row0 * D);
    for (int i = tid; i < RPB * (D / 4); i += 512) {
        int row = i >> 4, c4 = (i & 15) << 2;
        size_t grow = row0 + row;
        if (grow < NTOT) {
            float4 o;
            o.x = acc[row * ASTR + c4 + 0];
            o.y = acc[row * ASTR + c4 + 1];
            o.z = acc[row * ASTR + c4 + 2];
            o.w = acc[row * ASTR + c4 + 3];
            o4[i] = o;
        }
    }
}

// ---------- phase 2b: in-place out_row = leaky_relu(agg_row @ w) ----------

__global__ __launch_bounds__(256) void rowgemm_kernel(
    float* __restrict__ out, const float* __restrict__ w, int n)
{
    __shared__ float ws[D * D];   // 16 KB
    __shared__ float as[16 * D];  // 4 KB
    int tid = threadIdx.x;

    const float4* w4 = (const float4*)w;
    float4* ws4 = (float4*)ws;
    #pragma unroll
    for (int i = 0; i < 4; i++) ws4[tid + i * 256] = w4[tid + i * 256];

    size_t row0 = (size_t)blockIdx.x * 16;
    ((float4*)as)[tid] = ((const float4*)(out + row0 * D))[tid];
    __syncthreads();

    int col  = tid & 63;
    int rsub = tid >> 6;
    float res[4];
    #pragma unroll
    for (int rr = 0; rr < 4; rr++) {
        int row = rr * 4 + rsub;
        float acc = 0.f;
        #pragma unroll
        for (int k = 0; k < D; k++) {
            acc = fmaf(as[row * D + k], ws[k * D + col], acc);
        }
        res[rr] = acc > 0.f ? acc : 0.2f * acc;
    }
    #pragma unroll
    for (int rr = 0; rr < 4; rr++) {
        int row = rr * 4 + rsub;
        out[(row0 + row) * D + col] = res[rr];
    }
}

extern "C" void kernel_launch(void* const* d_in, const int* in_sizes, int n_in,
                              void* d_out, int out_size, void* d_ws, size_t ws_size,
                              hipStream_t stream) {
    const float* users_emb = (const float*)d_in[0];
    const float* items_emb = (const float*)d_in[1];
    const float* vals      = (const float*)d_in[2];
    const float* w         = (const float*)d_in[3];
    const int*   rows      = (const int*)d_in[4];
    const int*   cols      = (const int*)d_in[5];
    float* out = (float*)d_out;

    int nnz = in_sizes[2];
    int n   = NTOT;

    // workspace layout (bytes):
    //   blockhist  @ 0          : NBLK*NB ints (3.81 MB); reused as rowcnt
    //   coltotal   @ 4 MB       : NB ints
    //   bucketbase @ 4 MB+64K   : NB+1 ints
    //   bsums      @ 4 MB+192K  : 256 ints
    //   rowptr     @ 6 MB       : NTOT+1 ints (1.91 MB)
    //   rec2/order @ 8 MB       : nnz*8 B (80 MB)   [order: nnz*4 B]
    //   rec3       @ 88 MB      : nnz*8 B (80 MB)   [row-sorted {col,val}]
    char* ws = (char*)d_ws;
    int* blockhist  = (int*)(ws);
    int* rowcnt     = (int*)(ws);                       // reuse after scatter
    int* coltotal   = (int*)(ws + (4ull << 20));
    int* bucketbase = (int*)(ws + (4ull << 20) + (64ull << 10));
    int* bsums      = (int*)(ws + (4ull << 20) + (192ull << 10));
    int* rowptr     = (int*)(ws + (6ull << 20));
    void* recbuf    = (void*)(ws + (8ull << 20));
    void* rec3buf   = (void*)(ws + (88ull << 20));

    bool fast  = ws_size >= (8ull << 20) + (size_t)nnz * 8ull;
    bool fast3 = ws_size >= (88ull << 20) + (size_t)nnz * 8ull;

    hist_bucket<<<NBLK, 256, 0, stream>>>(rows, blockhist, nnz);
    colscan<<<(NB + 255) / 256, 256, 0, stream>>>(blockhist, coltotal);
    bucketscan<<<1, 256, 0, stream>>>(coltotal, bucketbase, nnz);

    if (fast3) {
        // exact per-row CSR + register-accumulation gather (proven structure)
        scatter_bucket<true><<<NBLK, 256, 0, stream>>>(
            rows, cols, vals, blockhist, bucketbase,
            nullptr, (int2*)recbuf, nnz);
        rowhist<<<NB, 256, 0, stream>>>(
            (const long long*)recbuf, bucketbase, rowcnt);
        int B = (n + SCAN_ELEMS - 1) / SCAN_ELEMS;   // 245 <= 256
        scan_reduce<<<B, 256, 0, stream>>>(rowcnt, bsums, n);
        scan_bsums<<<1, 256, 0, stream>>>(bsums, rowptr, B, n, nnz);
        scan_final<<<B, 256, 0, stream>>>(rowcnt, bsums, rowptr, n);
        rescatter<<<NB, 256, 0, stream>>>(
            (const long long*)recbuf, bucketbase, rowptr, (long long*)rec3buf);
        gather_rows<<<(n + 3) / 4, 256, 0, stream>>>(
            users_emb, items_emb, (const long long*)rec3buf, rowptr, out, n);
    } else if (fast) {
        scatter_bucket<true><<<NBLK, 256, 0, stream>>>(
            rows, cols, vals, blockhist, bucketbase,
            nullptr, (int2*)recbuf, nnz);
        accum_kernel<true><<<NB, 512, 0, stream>>>(
            users_emb, items_emb, vals, cols,
            (const long long*)recbuf, nullptr, bucketbase, out);
    } else {
        scatter_bucket<false><<<NBLK, 256, 0, stream>>>(
            rows, cols, vals, blockhist, bucketbase,
            (int*)recbuf, nullptr, nnz);
        accum_kernel<false><<<NB, 512, 0, stream>>>(
            users_emb, items_emb, vals, cols,
            nullptr, (const int*)recbuf, bucketbase, out);
    }

    rowgemm_kernel<<<n / 16, 256, 0, stream>>>(out, w, n);
}

// Round 9
// 1309.457 us; speedup vs baseline: 3.1545x; 1.2028x over previous
//
#include <hip/hip_runtime.h>
#include <hip/hip_bf16.h>

#define NUM_USER 300000
#define NUM_ITEM 200000
#define NTOT (NUM_USER + NUM_ITEM)
#define D 64
#define RPB 128                         // rows per bucket
#define NB ((NTOT + RPB - 1) / RPB)     // 3907 buckets
#define NBLK 256                        // edge-chunk blocks for hist/scatter
#define ASTR 65                         // padded LDS acc row stride (fallback)
#define AW 8                            // waves per accum block (fallback)
#define SCAN_ELEMS 2048

// ---------- phase 1a: per-block bucket histogram (LDS atomics only) ----------

__global__ __launch_bounds__(256) void hist_bucket(
    const int* __restrict__ rows, int* __restrict__ blockhist, int nnz)
{
    __shared__ int h[NB];   // 15.6 KB
    for (int i = threadIdx.x; i < NB; i += 256) h[i] = 0;
    __syncthreads();
    int chunk = (nnz + NBLK - 1) / NBLK;
    int lo = blockIdx.x * chunk;
    int hi = min(lo + chunk, nnz);
    for (int e = lo + threadIdx.x; e < hi; e += 256)
        atomicAdd(&h[__builtin_nontemporal_load(&rows[e]) >> 7], 1);
    __syncthreads();
    for (int i = threadIdx.x; i < NB; i += 256)
        blockhist[blockIdx.x * NB + i] = h[i];
}

// ---------- phase 1b: per-bucket exclusive scan across blocks ----------

__global__ __launch_bounds__(256) void colscan(
    int* __restrict__ blockhist, int* __restrict__ coltotal)
{
    int kb = blockIdx.x * 256 + threadIdx.x;
    if (kb >= NB) return;
    int sum = 0;
    for (int b = 0; b < NBLK; b++) {
        int v = blockhist[b * NB + kb];   // coalesced across lanes
        blockhist[b * NB + kb] = sum;
        sum += v;
    }
    coltotal[kb] = sum;
}

// ---------- phase 1c: exclusive scan of bucket totals (single block) ----------

__global__ __launch_bounds__(256) void bucketscan(
    const int* __restrict__ coltotal, int* __restrict__ bucketbase, int nnz)
{
    __shared__ int s[256];
    int t = threadIdx.x;
    int local[16];
    int sum = 0;
    #pragma unroll
    for (int i = 0; i < 16; i++) {
        int idx = t * 16 + i;
        int c = (idx < NB) ? coltotal[idx] : 0;
        local[i] = sum;       // exclusive within thread
        sum += c;
    }
    s[t] = sum;
    __syncthreads();
    int v = sum;
    for (int off = 1; off < 256; off <<= 1) {
        int add = (t >= off) ? s[t - off] : 0;
        __syncthreads();
        s[t] += add;
        __syncthreads();
    }
    int base = s[t] - v;      // exclusive across block
    #pragma unroll
    for (int i = 0; i < 16; i++) {
        int idx = t * 16 + i;
        if (idx < NB) bucketbase[idx] = base + local[i];
    }
    if (t == 255) bucketbase[NB] = base + sum;   // == nnz
}

// ---------- phase 1d: deterministic scatter into bucket segments ----------
// FAST: rec2[pos] = {(lrow<<19)|col, val}  (8B self-contained record)
// SLOW: order[pos] = (lrow<<24)|edge_id    (fallback if workspace < 88MB)

template<bool FAST>
__global__ __launch_bounds__(256) void scatter_bucket(
    const int* __restrict__ rows, const int* __restrict__ cols,
    const float* __restrict__ vals,
    const int* __restrict__ blockhist, const int* __restrict__ bucketbase,
    int* __restrict__ order, int2* __restrict__ rec2, int nnz)
{
    __shared__ int cur[NB];   // 15.6 KB
    for (int i = threadIdx.x; i < NB; i += 256)
        cur[i] = blockhist[blockIdx.x * NB + i] + bucketbase[i];
    __syncthreads();
    int chunk = (nnz + NBLK - 1) / NBLK;
    int lo = blockIdx.x * chunk;
    int hi = min(lo + chunk, nnz);
    for (int e = lo + threadIdx.x; e < hi; e += 256) {
        int r = __builtin_nontemporal_load(&rows[e]);
        int pos = atomicAdd(&cur[r >> 7], 1);     // LDS atomic, fast
        if (FAST) {
            int   c = __builtin_nontemporal_load(&cols[e]);
            float v = __builtin_nontemporal_load(&vals[e]);
            rec2[pos] = make_int2(((r & (RPB - 1)) << 19) | c,
                                  __float_as_int(v));
        } else {
            order[pos] = ((r & (RPB - 1)) << 24) | e;
        }
    }
}

// ---------- phase 1e: per-row counts from bucket-sorted records ----------

__global__ __launch_bounds__(256) void rowhist(
    const long long* __restrict__ rec2, const int* __restrict__ bucketbase,
    int* __restrict__ rowcnt)
{
    __shared__ int h[RPB];
    int t = threadIdx.x;
    if (t < RPB) h[t] = 0;
    __syncthreads();
    int kb = blockIdx.x;
    int start = bucketbase[kb], end = bucketbase[kb + 1];
    for (int i = start + t; i < end; i += 256) {
        int key = (int)(__builtin_nontemporal_load(&rec2[i]) & 0xffffffffLL);
        atomicAdd(&h[(key >> 19) & (RPB - 1)], 1);
    }
    __syncthreads();
    int row0 = kb * RPB;
    if (t < RPB && row0 + t < NTOT) rowcnt[row0 + t] = h[t];
}

// ---------- phase 1f: exclusive scan rowcnt -> rowptr (3 kernels, proven) ----

__global__ __launch_bounds__(256) void scan_reduce(
    const int* __restrict__ cnt, int* __restrict__ bsums, int n)
{
    __shared__ int s[256];
    int base = blockIdx.x * SCAN_ELEMS;
    int sum = 0;
    for (int i = threadIdx.x; i < SCAN_ELEMS; i += 256) {
        int idx = base + i;
        sum += (idx < n) ? cnt[idx] : 0;
    }
    s[threadIdx.x] = sum;
    __syncthreads();
    for (int off = 128; off > 0; off >>= 1) {
        if (threadIdx.x < off) s[threadIdx.x] += s[threadIdx.x + off];
        __syncthreads();
    }
    if (threadIdx.x == 0) bsums[blockIdx.x] = s[0];
}

__global__ __launch_bounds__(256) void scan_bsums(
    int* __restrict__ bsums, int* __restrict__ ptr, int B, int n, int nnz)
{
    __shared__ int s[256];
    int t = threadIdx.x;
    int v = (t < B) ? bsums[t] : 0;
    s[t] = v;
    __syncthreads();
    for (int off = 1; off < 256; off <<= 1) {
        int add = (t >= off) ? s[t - off] : 0;
        __syncthreads();
        s[t] += add;
        __syncthreads();
    }
    if (t < B) bsums[t] = s[t] - v;  // exclusive
    if (t == 0) ptr[n] = nnz;
}

__global__ __launch_bounds__(256) void scan_final(
    const int* __restrict__ cnt, const int* __restrict__ bsums,
    int* __restrict__ ptr, int n)
{
    __shared__ int s[256];
    int base = blockIdx.x * SCAN_ELEMS;
    int t = threadIdx.x;
    int local[8];
    int mysum = 0;
    #pragma unroll
    for (int i = 0; i < 8; i++) {
        int idx = base + t * 8 + i;
        int c = (idx < n) ? cnt[idx] : 0;
        local[i] = mysum;   // exclusive within thread
        mysum += c;
    }
    s[t] = mysum;
    __syncthreads();
    int v = mysum;
    for (int off = 1; off < 256; off <<= 1) {
        int add = (t >= off) ? s[t - off] : 0;
        __syncthreads();
        s[t] += add;
        __syncthreads();
    }
    int thread_base = bsums[blockIdx.x] + s[t] - v;  // exclusive across block
    #pragma unroll
    for (int i = 0; i < 8; i++) {
        int idx = base + t * 8 + i;
        if (idx < n) ptr[idx] = thread_base + local[i];
    }
}

// ---------- phase 1g: row-sort within bucket: rec2 -> rec3 = {col,val} ------
// rowptr[row0] == bucketbase[kb] (scans agree), so writes stay in-bucket.

__global__ __launch_bounds__(256) void rescatter(
    const long long* __restrict__ rec2, const int* __restrict__ bucketbase,
    const int* __restrict__ rowptr, long long* __restrict__ rec3)
{
    __shared__ int cur[RPB];
    int t = threadIdx.x;
    int kb = blockIdx.x;
    int row0 = kb * RPB;
    if (t < RPB) cur[t] = (row0 + t < NTOT) ? rowptr[row0 + t] : 0;
    __syncthreads();
    int start = bucketbase[kb], end = bucketbase[kb + 1];
    for (int i = start + t; i < end; i += 256) {
        long long rc = __builtin_nontemporal_load(&rec2[i]);
        int key = (int)(rc & 0xffffffffLL);
        int lr  = (key >> 19) & (RPB - 1);
        int pos = atomicAdd(&cur[lr], 1);        // LDS atomic
        long long outrec = (rc & 0xffffffff00000000LL)
                         | (unsigned int)(key & 0x7FFFF);
        rec3[pos] = outrec;                       // in-bucket window, L2-local
    }
}

// ---------- phase 2a: gather, one wave per row, quarter-wave float4 ---------
// rec3 is row-contiguous: lanes sub=lane>>4 read records g+sub directly
// (32B segment, broadcast over the 16 qi lanes) -> ZERO cross-lane ops in
// the inner loop; each lane accumulates 4 dims in a float4 register.
// One 8-shfl_xor reduce + one coalesced 256B store per row.

__global__ __launch_bounds__(256) void gather_rows(
    const float* __restrict__ users_emb, const float* __restrict__ items_emb,
    const long long* __restrict__ rec3, const int* __restrict__ rowptr,
    float* __restrict__ out, int n)
{
    int r = blockIdx.x * 4 + (threadIdx.x >> 6);
    if (r >= n) return;
    int lane = threadIdx.x & 63;
    int sub  = lane >> 4;      // which of 4 in-flight records this lane serves
    int qi   = lane & 15;      // 16B chunk of the 256B embedding row
    int k0 = rowptr[r];
    int k1 = rowptr[r + 1];
    float4 a = make_float4(0.f, 0.f, 0.f, 0.f);
    #pragma unroll 2
    for (int g = k0; g < k1; g += 4) {
        int k = g + sub;
        long long rc = __builtin_nontemporal_load(&rec3[k < k1 ? k : (k1 - 1)]);
        int   c = (int)(rc & 0x7FFFFLL);
        float v = (k < k1) ? __int_as_float((int)(rc >> 32)) : 0.f;
        const float* src = (c < NUM_USER)
            ? users_emb + (size_t)c * D
            : items_emb + (size_t)(c - NUM_USER) * D;
        float4 e4 = *(const float4*)(src + (qi << 2));
        a.x = fmaf(v, e4.x, a.x);
        a.y = fmaf(v, e4.y, a.y);
        a.z = fmaf(v, e4.z, a.z);
        a.w = fmaf(v, e4.w, a.w);
    }
    // reduce across the 4 sub-groups (lanes xor 16, then xor 32)
    a.x += __shfl_xor(a.x, 16); a.y += __shfl_xor(a.y, 16);
    a.z += __shfl_xor(a.z, 16); a.w += __shfl_xor(a.w, 16);
    a.x += __shfl_xor(a.x, 32); a.y += __shfl_xor(a.y, 32);
    a.z += __shfl_xor(a.z, 32); a.w += __shfl_xor(a.w, 32);
    if (sub == 0)
        *(float4*)(out + (size_t)r * D + (qi << 2)) = a;   // 256B per row
}

// ---------- fallback phase 2a (ws too small): bucket accum via LDS ----------

template<bool FAST>
__global__ __launch_bounds__(512) void accum_kernel(
    const float* __restrict__ users_emb, const float* __restrict__ items_emb,
    const float* __restrict__ vals, const int* __restrict__ cols,
    const long long* __restrict__ rec2, const int* __restrict__ order,
    const int* __restrict__ bucketbase, float* __restrict__ out)
{
    __shared__ float acc[RPB * ASTR];   // 33.3 KB
    int tid = threadIdx.x;
    for (int i = tid; i < RPB * ASTR; i += 512) acc[i] = 0.f;
    __syncthreads();

    int kb = blockIdx.x;
    int start = bucketbase[kb];
    int end   = bucketbase[kb + 1];
    int lane = tid & 63;
    int wid  = tid >> 6;
    int sub  = lane >> 4;
    int qi   = lane & 15;

    int span = end - start;
    int T = (span + (AW * 4 - 1)) / (AW * 4);
    int e0 = start + wid * 4 + sub;

    for (int it = 0; it < T; it++) {
        int e  = e0 + it * (AW * 4);
        int ec = max(start, min(e, end - 1));
        int ck; float v;
        if (FAST) {
            long long rc = __builtin_nontemporal_load(&rec2[ec]);
            ck = (int)(rc & 0xffffffffLL);
            v  = (e < end) ? __int_as_float((int)(rc >> 32)) : 0.f;
        } else {
            int rec  = __builtin_nontemporal_load(&order[ec]);
            int eid  = rec & 0xFFFFFF;
            int lrow = rec >> 24;
            ck = __builtin_nontemporal_load(&cols[eid]) | (lrow << 19);
            v  = (e < end) ? __builtin_nontemporal_load(&vals[eid]) : 0.f;
        }
        int cj = ck & 0x7FFFF;
        int lr = (ck >> 19) & (RPB - 1);
        const float* src = (cj < NUM_USER)
            ? users_emb + (size_t)cj * D
            : items_emb + (size_t)(cj - NUM_USER) * D;
        float4 e4 = *(const float4*)(src + (qi << 2));
        int ab = lr * ASTR + (qi << 2);
        atomicAdd(&acc[ab + 0], v * e4.x);
        atomicAdd(&acc[ab + 1], v * e4.y);
        atomicAdd(&acc[ab + 2], v * e4.z);
        atomicAdd(&acc[ab + 3], v * e4.w);
    }
    __syncthreads();

    size_t row0 = (size_t)kb * RPB;
    float4* o4 = (float4*)(out + row0 * D);
    for (int i = tid; i < RPB * (D / 4); i += 512) {
        int row = i >> 4, c4 = (i & 15) << 2;
        size_t grow = row0 + row;
        if (grow < NTOT) {
            float4 o;
            o.x = acc[row * ASTR + c4 + 0];
            o.y = acc[row * ASTR + c4 + 1];
            o.z = acc[row * ASTR + c4 + 2];
            o.w = acc[row * ASTR + c4 + 3];
            o4[i] = o;
        }
    }
}

// ---------- phase 2b: in-place out_row = leaky_relu(agg_row @ w) ----------

__global__ __launch_bounds__(256) void rowgemm_kernel(
    float* __restrict__ out, const float* __restrict__ w, int n)
{
    __shared__ float ws[D * D];   // 16 KB
    __shared__ float as[16 * D];  // 4 KB
    int tid = threadIdx.x;

    const float4* w4 = (const float4*)w;
    float4* ws4 = (float4*)ws;
    #pragma unroll
    for (int i = 0; i < 4; i++) ws4[tid + i * 256] = w4[tid + i * 256];

    size_t row0 = (size_t)blockIdx.x * 16;
    ((float4*)as)[tid] = ((const float4*)(out + row0 * D))[tid];
    __syncthreads();

    int col  = tid & 63;
    int rsub = tid >> 6;
    float res[4];
    #pragma unroll
    for (int rr = 0; rr < 4; rr++) {
        int row = rr * 4 + rsub;
        float acc = 0.f;
        #pragma unroll
        for (int k = 0; k < D; k++) {
            acc = fmaf(as[row * D + k], ws[k * D + col], acc);
        }
        res[rr] = acc > 0.f ? acc : 0.2f * acc;
    }
    #pragma unroll
    for (int rr = 0; rr < 4; rr++) {
        int row = rr * 4 + rsub;
        out[(row0 + row) * D + col] = res[rr];
    }
}

extern "C" void kernel_launch(void* const* d_in, const int* in_sizes, int n_in,
                              void* d_out, int out_size, void* d_ws, size_t ws_size,
                              hipStream_t stream) {
    const float* users_emb = (const float*)d_in[0];
    const float* items_emb = (const float*)d_in[1];
    const float* vals      = (const float*)d_in[2];
    const float* w         = (const float*)d_in[3];
    const int*   rows      = (const int*)d_in[4];
    const int*   cols      = (const int*)d_in[5];
    float* out = (float*)d_out;

    int nnz = in_sizes[2];
    int n   = NTOT;

    // workspace layout (bytes):
    //   blockhist  @ 0          : NBLK*NB ints (3.81 MB); reused as rowcnt
    //   coltotal   @ 4 MB       : NB ints
    //   bucketbase @ 4 MB+64K   : NB+1 ints
    //   bsums      @ 4 MB+192K  : 256 ints
    //   rowptr     @ 6 MB       : NTOT+1 ints (1.91 MB)
    //   rec2/order @ 8 MB       : nnz*8 B (80 MB)   [order: nnz*4 B]
    //   rec3       @ 88 MB      : nnz*8 B (80 MB)   [row-sorted {col,val}]
    char* ws = (char*)d_ws;
    int* blockhist  = (int*)(ws);
    int* rowcnt     = (int*)(ws);                       // reuse after scatter
    int* coltotal   = (int*)(ws + (4ull << 20));
    int* bucketbase = (int*)(ws + (4ull << 20) + (64ull << 10));
    int* bsums      = (int*)(ws + (4ull << 20) + (192ull << 10));
    int* rowptr     = (int*)(ws + (6ull << 20));
    void* recbuf    = (void*)(ws + (8ull << 20));
    void* rec3buf   = (void*)(ws + (88ull << 20));

    bool fast  = ws_size >= (8ull << 20) + (size_t)nnz * 8ull;
    bool fast3 = ws_size >= (88ull << 20) + (size_t)nnz * 8ull;

    hist_bucket<<<NBLK, 256, 0, stream>>>(rows, blockhist, nnz);
    colscan<<<(NB + 255) / 256, 256, 0, stream>>>(blockhist, coltotal);
    bucketscan<<<1, 256, 0, stream>>>(coltotal, bucketbase, nnz);

    if (fast3) {
        // exact per-row CSR + quarter-wave register-accumulation gather
        scatter_bucket<true><<<NBLK, 256, 0, stream>>>(
            rows, cols, vals, blockhist, bucketbase,
            nullptr, (int2*)recbuf, nnz);
        rowhist<<<NB, 256, 0, stream>>>(
            (const long long*)recbuf, bucketbase, rowcnt);
        int B = (n + SCAN_ELEMS - 1) / SCAN_ELEMS;   // 245 <= 256
        scan_reduce<<<B, 256, 0, stream>>>(rowcnt, bsums, n);
        scan_bsums<<<1, 256, 0, stream>>>(bsums, rowptr, B, n, nnz);
        scan_final<<<B, 256, 0, stream>>>(rowcnt, bsums, rowptr, n);
        rescatter<<<NB, 256, 0, stream>>>(
            (const long long*)recbuf, bucketbase, rowptr, (long long*)rec3buf);
        gather_rows<<<(n + 3) / 4, 256, 0, stream>>>(
            users_emb, items_emb, (const long long*)rec3buf, rowptr, out, n);
    } else if (fast) {
        scatter_bucket<true><<<NBLK, 256, 0, stream>>>(
            rows, cols, vals, blockhist, bucketbase,
            nullptr, (int2*)recbuf, nnz);
        accum_kernel<true><<<NB, 512, 0, stream>>>(
            users_emb, items_emb, vals, cols,
            (const long long*)recbuf, nullptr, bucketbase, out);
    } else {
        scatter_bucket<false><<<NBLK, 256, 0, stream>>>(
            rows, cols, vals, blockhist, bucketbase,
            (int*)recbuf, nullptr, nnz);
        accum_kernel<false><<<NB, 512, 0, stream>>>(
            users_emb, items_emb, vals, cols,
            nullptr, (const int*)recbuf, bucketbase, out);
    }

    rowgemm_kernel<<<n / 16, 256, 0, stream>>>(out, w, n);
}

// Round 10
// 1212.249 us; speedup vs baseline: 3.4075x; 1.0802x over previous
//
#include <hip/hip_runtime.h>
#include <hip/hip_bf16.h>

#define NUM_USER 300000
#define NUM_ITEM 200000
#define NTOT (NUM_USER + NUM_ITEM)
#define D 64
#define RPB 128                         // rows per bucket
#define NB ((NTOT + RPB - 1) / RPB)     // 3907 buckets
#define NBLK 256                        // edge-chunk blocks for hist/scatter
#define ASTR 65                         // padded LDS acc row stride (fallback)
#define AW 8                            // waves per accum block (fallback)

// ---------- phase 1a: per-block bucket histogram (LDS atomics only) ----------

__global__ __launch_bounds__(256) void hist_bucket(
    const int* __restrict__ rows, int* __restrict__ blockhist, int nnz)
{
    __shared__ int h[NB];   // 15.6 KB
    for (int i = threadIdx.x; i < NB; i += 256) h[i] = 0;
    __syncthreads();
    int chunk = (nnz + NBLK - 1) / NBLK;
    int lo = blockIdx.x * chunk;
    int hi = min(lo + chunk, nnz);
    for (int e = lo + threadIdx.x; e < hi; e += 256)
        atomicAdd(&h[__builtin_nontemporal_load(&rows[e]) >> 7], 1);
    __syncthreads();
    for (int i = threadIdx.x; i < NB; i += 256)
        blockhist[blockIdx.x * NB + i] = h[i];
}

// ---------- phase 1b: per-bucket exclusive scan across blocks ----------

__global__ __launch_bounds__(256) void colscan(
    int* __restrict__ blockhist, int* __restrict__ coltotal)
{
    int kb = blockIdx.x * 256 + threadIdx.x;
    if (kb >= NB) return;
    int sum = 0;
    for (int b = 0; b < NBLK; b++) {
        int v = blockhist[b * NB + kb];   // coalesced across lanes
        blockhist[b * NB + kb] = sum;
        sum += v;
    }
    coltotal[kb] = sum;
}

// ---------- phase 1c: exclusive scan of bucket totals (single block) ----------

__global__ __launch_bounds__(256) void bucketscan(
    const int* __restrict__ coltotal, int* __restrict__ bucketbase, int nnz)
{
    __shared__ int s[256];
    int t = threadIdx.x;
    int local[16];
    int sum = 0;
    #pragma unroll
    for (int i = 0; i < 16; i++) {
        int idx = t * 16 + i;
        int c = (idx < NB) ? coltotal[idx] : 0;
        local[i] = sum;       // exclusive within thread
        sum += c;
    }
    s[t] = sum;
    __syncthreads();
    int v = sum;
    for (int off = 1; off < 256; off <<= 1) {
        int add = (t >= off) ? s[t - off] : 0;
        __syncthreads();
        s[t] += add;
        __syncthreads();
    }
    int base = s[t] - v;      // exclusive across block
    #pragma unroll
    for (int i = 0; i < 16; i++) {
        int idx = t * 16 + i;
        if (idx < NB) bucketbase[idx] = base + local[i];
    }
    if (t == 255) bucketbase[NB] = base + sum;   // == nnz
}

// ---------- phase 1d: deterministic scatter into bucket segments ----------
// FAST: rec2[pos] = {(lrow<<19)|col, val}  (8B self-contained record)
// SLOW: order[pos] = (lrow<<24)|edge_id    (fallback if workspace < 88MB)

template<bool FAST>
__global__ __launch_bounds__(256) void scatter_bucket(
    const int* __restrict__ rows, const int* __restrict__ cols,
    const float* __restrict__ vals,
    const int* __restrict__ blockhist, const int* __restrict__ bucketbase,
    int* __restrict__ order, int2* __restrict__ rec2, int nnz)
{
    __shared__ int cur[NB];   // 15.6 KB
    for (int i = threadIdx.x; i < NB; i += 256)
        cur[i] = blockhist[blockIdx.x * NB + i] + bucketbase[i];
    __syncthreads();
    int chunk = (nnz + NBLK - 1) / NBLK;
    int lo = blockIdx.x * chunk;
    int hi = min(lo + chunk, nnz);
    for (int e = lo + threadIdx.x; e < hi; e += 256) {
        int r = __builtin_nontemporal_load(&rows[e]);
        int pos = atomicAdd(&cur[r >> 7], 1);     // LDS atomic, fast
        if (FAST) {
            int   c = __builtin_nontemporal_load(&cols[e]);
            float v = __builtin_nontemporal_load(&vals[e]);
            rec2[pos] = make_int2(((r & (RPB - 1)) << 19) | c,
                                  __float_as_int(v));
        } else {
            order[pos] = ((r & (RPB - 1)) << 24) | e;
        }
    }
}

// ---------- phase 1e (fused): per-bucket count+scan -> rowptr, row-sort -----
// rowptr[row0+t] = bucketbase[kb] + excl_scan(bucket-local counts): the
// global scan is redundant given bucketbase, so one kernel replaces
// rowhist + scan_reduce + scan_bsums + scan_final + rescatter.
// Bucket segment (~20KB) is L2-hot for the second pass.

__global__ __launch_bounds__(256) void rescatter2(
    const long long* __restrict__ rec2, const int* __restrict__ bucketbase,
    int* __restrict__ rowptr, long long* __restrict__ rec3)
{
    __shared__ int cnt[RPB];
    __shared__ int cur[RPB];
    __shared__ int s[256];
    int t = threadIdx.x;
    int kb = blockIdx.x;
    int row0 = kb * RPB;
    int start = bucketbase[kb], end = bucketbase[kb + 1];

    if (t < RPB) cnt[t] = 0;
    __syncthreads();
    // pass 1: count per-row
    for (int i = start + t; i < end; i += 256) {
        int key = (int)(rec2[i] & 0xffffffffLL);
        atomicAdd(&cnt[(key >> 19) & (RPB - 1)], 1);
    }
    __syncthreads();
    // 128-wide exclusive scan (proven bucketscan pattern, padded to 256)
    int v = (t < RPB) ? cnt[t] : 0;
    s[t] = v;
    __syncthreads();
    for (int off = 1; off < 256; off <<= 1) {
        int add = (t >= off) ? s[t - off] : 0;
        __syncthreads();
        s[t] += add;
        __syncthreads();
    }
    if (t < RPB) {
        int excl = s[t] - v;
        int p = start + excl;
        cur[t] = p;
        if (row0 + t <= NTOT) rowptr[row0 + t] = p;  // incl. rowptr[NTOT]=nnz
    }
    __syncthreads();
    // pass 2: scatter row-sorted self-contained records {val, col}
    for (int i = start + t; i < end; i += 256) {
        long long rc = rec2[i];
        int key = (int)(rc & 0xffffffffLL);
        int lr  = (key >> 19) & (RPB - 1);
        int pos = atomicAdd(&cur[lr], 1);        // LDS atomic
        long long outrec = (rc & 0xffffffff00000000LL)
                         | (unsigned int)(key & 0x7FFFF);
        rec3[pos] = outrec;                       // in-bucket window, L2-local
    }
}

// ---------- phase 2a: gather, one wave per row, quarter-wave float4 ---------
// ILP version: 8 records/iter with TWO independent accumulators so the
// compiler keeps >=2 gather loads in flight per wave (R9's VGPR=16 build
// serialized on one outstanding load -> latency-bound at 422us).

__global__ __launch_bounds__(256) void gather_rows(
    const float* __restrict__ users_emb, const float* __restrict__ items_emb,
    const long long* __restrict__ rec3, const int* __restrict__ rowptr,
    float* __restrict__ out, int n)
{
    int r = blockIdx.x * 4 + (threadIdx.x >> 6);
    if (r >= n) return;
    int lane = threadIdx.x & 63;
    int sub  = lane >> 4;      // which of 4 in-flight records this lane serves
    int qi   = lane & 15;      // 16B chunk of the 256B embedding row
    int k0 = rowptr[r];
    int k1 = rowptr[r + 1];
    float4 a0 = make_float4(0.f, 0.f, 0.f, 0.f);
    float4 a1 = make_float4(0.f, 0.f, 0.f, 0.f);
    #pragma unroll 2
    for (int g = k0; g < k1; g += 8) {
        int ka = g + sub;
        int kb = g + 4 + sub;
        long long rca = __builtin_nontemporal_load(&rec3[ka < k1 ? ka : k1 - 1]);
        long long rcb = __builtin_nontemporal_load(&rec3[kb < k1 ? kb : k1 - 1]);
        int   ca = (int)(rca & 0x7FFFFLL);
        int   cb = (int)(rcb & 0x7FFFFLL);
        float va = (ka < k1) ? __int_as_float((int)(rca >> 32)) : 0.f;
        float vb = (kb < k1) ? __int_as_float((int)(rcb >> 32)) : 0.f;
        const float* sa = (ca < NUM_USER)
            ? users_emb + (size_t)ca * D
            : items_emb + (size_t)(ca - NUM_USER) * D;
        const float* sb = (cb < NUM_USER)
            ? users_emb + (size_t)cb * D
            : items_emb + (size_t)(cb - NUM_USER) * D;
        float4 ea = *(const float4*)(sa + (qi << 2));
        float4 eb = *(const float4*)(sb + (qi << 2));
        a0.x = fmaf(va, ea.x, a0.x); a0.y = fmaf(va, ea.y, a0.y);
        a0.z = fmaf(va, ea.z, a0.z); a0.w = fmaf(va, ea.w, a0.w);
        a1.x = fmaf(vb, eb.x, a1.x); a1.y = fmaf(vb, eb.y, a1.y);
        a1.z = fmaf(vb, eb.z, a1.z); a1.w = fmaf(vb, eb.w, a1.w);
    }
    float4 a;
    a.x = a0.x + a1.x; a.y = a0.y + a1.y;
    a.z = a0.z + a1.z; a.w = a0.w + a1.w;
    // reduce across the 4 sub-groups (lanes xor 16, then xor 32)
    a.x += __shfl_xor(a.x, 16); a.y += __shfl_xor(a.y, 16);
    a.z += __shfl_xor(a.z, 16); a.w += __shfl_xor(a.w, 16);
    a.x += __shfl_xor(a.x, 32); a.y += __shfl_xor(a.y, 32);
    a.z += __shfl_xor(a.z, 32); a.w += __shfl_xor(a.w, 32);
    if (sub == 0)
        *(float4*)(out + (size_t)r * D + (qi << 2)) = a;   // 256B per row
}

// ---------- fallback phase 2a (ws too small): bucket accum via LDS ----------

template<bool FAST>
__global__ __launch_bounds__(512) void accum_kernel(
    const float* __restrict__ users_emb, const float* __restrict__ items_emb,
    const float* __restrict__ vals, const int* __restrict__ cols,
    const long long* __restrict__ rec2, const int* __restrict__ order,
    const int* __restrict__ bucketbase, float* __restrict__ out)
{
    __shared__ float acc[RPB * ASTR];   // 33.3 KB
    int tid = threadIdx.x;
    for (int i = tid; i < RPB * ASTR; i += 512) acc[i] = 0.f;
    __syncthreads();

    int kb = blockIdx.x;
    int start = bucketbase[kb];
    int end   = bucketbase[kb + 1];
    int lane = tid & 63;
    int wid  = tid >> 6;
    int sub  = lane >> 4;
    int qi   = lane & 15;

    int span = end - start;
    int T = (span + (AW * 4 - 1)) / (AW * 4);
    int e0 = start + wid * 4 + sub;

    for (int it = 0; it < T; it++) {
        int e  = e0 + it * (AW * 4);
        int ec = max(start, min(e, end - 1));
        int ck; float v;
        if (FAST) {
            long long rc = __builtin_nontemporal_load(&rec2[ec]);
            ck = (int)(rc & 0xffffffffLL);
            v  = (e < end) ? __int_as_float((int)(rc >> 32)) : 0.f;
        } else {
            int rec  = __builtin_nontemporal_load(&order[ec]);
            int eid  = rec & 0xFFFFFF;
            int lrow = rec >> 24;
            ck = __builtin_nontemporal_load(&cols[eid]) | (lrow << 19);
            v  = (e < end) ? __builtin_nontemporal_load(&vals[eid]) : 0.f;
        }
        int cj = ck & 0x7FFFF;
        int lr = (ck >> 19) & (RPB - 1);
        const float* src = (cj < NUM_USER)
            ? users_emb + (size_t)cj * D
            : items_emb + (size_t)(cj - NUM_USER) * D;
        float4 e4 = *(const float4*)(src + (qi << 2));
        int ab = lr * ASTR + (qi << 2);
        atomicAdd(&acc[ab + 0], v * e4.x);
        atomicAdd(&acc[ab + 1], v * e4.y);
        atomicAdd(&acc[ab + 2], v * e4.z);
        atomicAdd(&acc[ab + 3], v * e4.w);
    }
    __syncthreads();

    size_t row0 = (size_t)kb * RPB;
    float4* o4 = (float4*)(out + row0 * D);
    for (int i = tid; i < RPB * (D / 4); i += 512) {
        int row = i >> 4, c4 = (i & 15) << 2;
        size_t grow = row0 + row;
        if (grow < NTOT) {
            float4 o;
            o.x = acc[row * ASTR + c4 + 0];
            o.y = acc[row * ASTR + c4 + 1];
            o.z = acc[row * ASTR + c4 + 2];
            o.w = acc[row * ASTR + c4 + 3];
            o4[i] = o;
        }
    }
}

// ---------- phase 2b: in-place out_row = leaky_relu(agg_row @ w) ----------

__global__ __launch_bounds__(256) void rowgemm_kernel(
    float* __restrict__ out, const float* __restrict__ w, int n)
{
    __shared__ float ws[D * D];   // 16 KB
    __shared__ float as[16 * D];  // 4 KB
    int tid = threadIdx.x;

    const float4* w4 = (const float4*)w;
    float4* ws4 = (float4*)ws;
    #pragma unroll
    for (int i = 0; i < 4; i++) ws4[tid + i * 256] = w4[tid + i * 256];

    size_t row0 = (size_t)blockIdx.x * 16;
    ((float4*)as)[tid] = ((const float4*)(out + row0 * D))[tid];
    __syncthreads();

    int col  = tid & 63;
    int rsub = tid >> 6;
    float res[4];
    #pragma unroll
    for (int rr = 0; rr < 4; rr++) {
        int row = rr * 4 + rsub;
        float acc = 0.f;
        #pragma unroll
        for (int k = 0; k < D; k++) {
            acc = fmaf(as[row * D + k], ws[k * D + col], acc);
        }
        res[rr] = acc > 0.f ? acc : 0.2f * acc;
    }
    #pragma unroll
    for (int rr = 0; rr < 4; rr++) {
        int row = rr * 4 + rsub;
        out[(row0 + row) * D + col] = res[rr];
    }
}

extern "C" void kernel_launch(void* const* d_in, const int* in_sizes, int n_in,
                              void* d_out, int out_size, void* d_ws, size_t ws_size,
                              hipStream_t stream) {
    const float* users_emb = (const float*)d_in[0];
    const float* items_emb = (const float*)d_in[1];
    const float* vals      = (const float*)d_in[2];
    const float* w         = (const float*)d_in[3];
    const int*   rows      = (const int*)d_in[4];
    const int*   cols      = (const int*)d_in[5];
    float* out = (float*)d_out;

    int nnz = in_sizes[2];
    int n   = NTOT;

    // workspace layout (bytes):
    //   blockhist  @ 0          : NBLK*NB ints (3.81 MB)
    //   coltotal   @ 4 MB       : NB ints
    //   bucketbase @ 4 MB+64K   : NB+1 ints
    //   rowptr     @ 6 MB       : NTOT+1 ints (1.91 MB)
    //   rec2/order @ 8 MB       : nnz*8 B (80 MB)   [order: nnz*4 B]
    //   rec3       @ 88 MB      : nnz*8 B (80 MB)   [row-sorted {col,val}]
    char* ws = (char*)d_ws;
    int* blockhist  = (int*)(ws);
    int* coltotal   = (int*)(ws + (4ull << 20));
    int* bucketbase = (int*)(ws + (4ull << 20) + (64ull << 10));
    int* rowptr     = (int*)(ws + (6ull << 20));
    void* recbuf    = (void*)(ws + (8ull << 20));
    void* rec3buf   = (void*)(ws + (88ull << 20));

    bool fast  = ws_size >= (8ull << 20) + (size_t)nnz * 8ull;
    bool fast3 = ws_size >= (88ull << 20) + (size_t)nnz * 8ull;

    hist_bucket<<<NBLK, 256, 0, stream>>>(rows, blockhist, nnz);
    colscan<<<(NB + 255) / 256, 256, 0, stream>>>(blockhist, coltotal);
    bucketscan<<<1, 256, 0, stream>>>(coltotal, bucketbase, nnz);

    if (fast3) {
        // exact per-row CSR (fused local scan) + ILP register gather
        scatter_bucket<true><<<NBLK, 256, 0, stream>>>(
            rows, cols, vals, blockhist, bucketbase,
            nullptr, (int2*)recbuf, nnz);
        rescatter2<<<NB, 256, 0, stream>>>(
            (const long long*)recbuf, bucketbase, rowptr, (long long*)rec3buf);
        gather_rows<<<(n + 3) / 4, 256, 0, stream>>>(
            users_emb, items_emb, (const long long*)rec3buf, rowptr, out, n);
    } else if (fast) {
        scatter_bucket<true><<<NBLK, 256, 0, stream>>>(
            rows, cols, vals, blockhist, bucketbase,
            nullptr, (int2*)recbuf, nnz);
        accum_kernel<true><<<NB, 512, 0, stream>>>(
            users_emb, items_emb, vals, cols,
            (const long long*)recbuf, nullptr, bucketbase, out);
    } else {
        scatter_bucket<false><<<NBLK, 256, 0, stream>>>(
            rows, cols, vals, blockhist, bucketbase,
            (int*)recbuf, nullptr, nnz);
        accum_kernel<false><<<NB, 512, 0, stream>>>(
            users_emb, items_emb, vals, cols,
            nullptr, (const int*)recbuf, bucketbase, out);
    }

    rowgemm_kernel<<<n / 16, 256, 0, stream>>>(out, w, n);
}